// Round 13
// baseline (6064.563 us; speedup 1.0000x reference)
//
#include <hip/hip_runtime.h>
#include <math.h>

// ---------------------------------------------------------------------------
// 4-layer LSTM, B=64 T=512 D=H=1024. Persistent cooperative kernel, wavefront
// schedule (layer l works on t = s - l). Round-13 = round-12 with the LDS
// A-read redundancy removed:
//   - Wave role {mat(2) x kq(4)}, ALL 4 gates per wave: bw[4][8]=128 regs
//     (gate g, K=256 quarter), acc[4][4]=64. Each A-fragment feeds 4 MFMAs
//     (was 2) -> A-read traffic halves to 256 KB/step/CU.
//     (r6 spilled with this role; r11's gload_lds staging removed ~35 regs
//     of staging state, so demand now ~225 < 256. WRITE_SIZE is the
//     spill tripwire.)
//   - Chunk layout [mat][kq][b(64)][4 sl x 16B] (64B rows, K=32 per kq per
//     chunk, 8 chunks/step). Read quads (row&1, lq) get exactly 8 lanes
//     each = even = b128 floor; NO swizzle needed (write side linear too).
//   - Reduction: 4 kq-planes f32[4][64][64] (64 KB, overlay both staging
//     buffers after final compute sync), bp = b ^ ((v&7)<<2) (r7-proven):
//     mat0 writes plane[kq], sync, mat1 accumulates, sync, gate threads
//     sum 4 planes.
// Unchanged from r12 (verified): gload_lds staging (linear dest), coalesced
// gate mapping gb=tid>>3/gc=(tid&7)*2 (h-store 8x32B bursts), fast gates,
// relaxed-agent single-hop barrier + one acquire fence, h16 parity double
// buffer, c-state in registers.
// ---------------------------------------------------------------------------

#define BSZ 64
#define TSZ 512
#define DSZ 1024
#define HSZ 1024
#define LSZ 4
#define NBLK 256
#define NTHR 512
#define NSTEP (TSZ + LSZ - 1)   // 515
#define BUFB 32768               // bytes per LDS staging buffer

typedef _Float16 half8  __attribute__((ext_vector_type(8)));
typedef _Float16 half4  __attribute__((ext_vector_type(4)));
typedef _Float16 half2v __attribute__((ext_vector_type(2)));
typedef float    f32x4  __attribute__((ext_vector_type(4)));
typedef float    f32x8  __attribute__((ext_vector_type(8)));

// workspace layout (bytes)
constexpr size_t N_X  = (size_t)BSZ * TSZ * DSZ;       // halfs
constexpr size_t N_H  = (size_t)2 * LSZ * BSZ * HSZ;   // halfs (h double buffer)
constexpr size_t OFF_X     = 0;
constexpr size_t OFF_H     = OFF_X + N_X * 2;
constexpr size_t OFF_FLAGS = OFF_H + N_H * 2;          // 256 flags, 64B apart
constexpr size_t BAR_BYTES = (size_t)NBLK * 64;

// fast gates (r11/r12-verified: absmax unchanged at 4.88e-4)
__device__ inline float fsig(float x) {
  return __builtin_amdgcn_rcpf(1.0f + __expf(-x));
}
__device__ inline float ftanh(float x) {
  float e = __expf(fminf(2.0f * x, 80.0f));
  return 1.0f - 2.0f * __builtin_amdgcn_rcpf(e + 1.0f);
}

__device__ inline void gload16(const void* g, void* l) {
  __builtin_amdgcn_global_load_lds(
      (const __attribute__((address_space(1))) void*)g,
      (__attribute__((address_space(3))) void*)l, 16, 0, 0);
}

// Single-hop all-poll grid barrier (r6-r12-verified).
__device__ inline void gbar(unsigned* flags, unsigned tgt) {
  __syncthreads();
  const int t = threadIdx.x;
  if (t == 0)
    __hip_atomic_store(&flags[(size_t)blockIdx.x * 16], tgt, __ATOMIC_RELAXED,
                       __HIP_MEMORY_SCOPE_AGENT);
  if (t < NBLK) {
    while (__hip_atomic_load(&flags[(size_t)t * 16], __ATOMIC_RELAXED,
                             __HIP_MEMORY_SCOPE_AGENT) < tgt)
      __builtin_amdgcn_s_sleep(2);
  }
  __syncthreads();
  if (t == 0) __builtin_amdgcn_fence(__ATOMIC_ACQUIRE, "agent");
  __syncthreads();
}

__global__ __launch_bounds__(NTHR, 1) void lstm_persistent(
    const float* __restrict__ xin, const float* __restrict__ Wih,
    const float* __restrict__ Whh, const float* __restrict__ bih,
    const float* __restrict__ bhh, float* __restrict__ out,
    char* __restrict__ ws)
{
  _Float16* x16   = (_Float16*)(ws + OFF_X);
  _Float16* h16   = (_Float16*)(ws + OFF_H);
  unsigned* flags = (unsigned*)(ws + OFF_FLAGS);

  const int tid  = threadIdx.x;
  const int gtid = blockIdx.x * NTHR + tid;
  const int lane = tid & 63;
  const int w    = tid >> 6;        // wave 0..7
  const int mat  = w >> 2;          // 0 = input-side, 1 = recurrent
  const int kq   = w & 3;           // K-quarter (256 k's)
  const int ln15 = lane & 15;
  const int lq   = lane >> 4;

  const int l  = blockIdx.x >> 6;   // layer
  const int cc = blockIdx.x & 63;   // column chunk (16 H-cols)
  const int c0 = cc * 16;

  // ---- weight preload (fp32 -> fp16, one time) ----
  // B-frag (r3-r12-verified convention): lane holds W[row = gate g,
  // col c0+ln15] at k = kq*256 + kc*32 + lq*8 + 0..7. bw[4][8] = 128 regs.
  const float* Wsel = mat ? Whh : Wih;
  half8 bw[4][8];
#pragma unroll
  for (int g = 0; g < 4; ++g) {
    const float* wrow =
        Wsel + (size_t)(l * 4096 + g * 1024 + c0 + ln15) * 1024 + kq * 256;
#pragma unroll
    for (int kc = 0; kc < 8; ++kc) {
      f32x8 f = *(const f32x8*)(wrow + kc * 32 + lq * 8);
      bw[g][kc] = __builtin_convertvector(f, half8);
    }
  }

  // ---- gate-math ownership (coalesced, r12-verified): row gb, cols gc/gc+1
  const int gb = tid >> 3;          // batch row 0..63
  const int gc = (tid & 7) * 2;     // even col 0..14
  float bsg[4][2];
#pragma unroll
  for (int g = 0; g < 4; ++g) {
    const int bb = l * 4096 + g * 1024 + c0 + gc;
    bsg[g][0] = bih[bb] + bhh[bb];
    bsg[g][1] = bih[bb + 1] + bhh[bb + 1];
  }
  float cr0 = 0.f, cr1 = 0.f;       // block-private c-state (registers)

  // ---- staging decomposition (step-invariant) ----
  // Chunk = [mat(2)][kq(4)][b(64)][4 sl x 16B] = 32KB, LDS LINEAR.
  // idx = it*512 + tid: mat_i = it>>1, kq_i = (2*it + hi)&3 (hi = tid>>8,
  // wave-uniform), b = (tid&255)>>2, sl = tid&3. Source byte in row b:
  // kq_i*512 + kc*64 + sl*16 (no swizzle).
  const int sb   = (tid & 255) >> 2;   // my staging batch row
  const int ssl  = (tid & 3) << 4;     // source slot byte
  const int hi   = tid >> 8;           // wave-uniform
  const int dstb = (tid >> 6) << 10;   // wave LDS base (w*1024)

  // ---- pre-phase: cast x to fp16, zero h — relaxed agent stores ----
  {
    const f32x4* s4 = (const f32x4*)xin;
    unsigned long long* xu = (unsigned long long*)x16;
    for (int i = gtid; i < (int)(N_X / 4); i += NBLK * NTHR) {
      half4 v = __builtin_convertvector(s4[i], half4);
      __hip_atomic_store(&xu[i], __builtin_bit_cast(unsigned long long, v),
                         __ATOMIC_RELAXED, __HIP_MEMORY_SCOPE_AGENT);
    }
    unsigned long long* hz = (unsigned long long*)h16;
    for (int i = gtid; i < (int)(N_H / 4); i += NBLK * NTHR)
      __hip_atomic_store(&hz[i], 0ull, __ATOMIC_RELAXED,
                         __HIP_MEMORY_SCOPE_AGENT);
  }
  unsigned btgt = 1;
  gbar(flags, btgt++);

  // ---- LDS: 2 staging buffers (32KB); 4 kq-planes overlay both (64KB) ----
  __shared__ __align__(16) char smem[2 * BUFB];
  float* pl = (float*)smem;        // f32[4][64][64] after final compute sync

  const int lm1 = (l > 0) ? (l - 1) : 0;

  for (int s = 0; s < NSTEP; ++s) {
    const int t = s - l;
    if (t >= 0 && t < TSZ) {
      const int prevslot = (s + 1) & 1;
      const _Float16* hin  = h16 + (size_t)prevslot * (LSZ * BSZ * HSZ) +
                             (size_t)lm1 * (BSZ * HSZ);
      const _Float16* hown = h16 + (size_t)prevslot * (LSZ * BSZ * HSZ) +
                             (size_t)l * (BSZ * HSZ);
      const _Float16* base0 = (l == 0) ? x16 + (size_t)t * DSZ : hin;
      const size_t    str0  = (l == 0) ? (size_t)TSZ * DSZ : (size_t)HSZ;

      // my two source rows for staging (mat0-side, mat1-side)
      const char* p0 = (const char*)(base0 + (size_t)sb * str0) + ssl;
      const char* p1 = (const char*)(hown + (size_t)sb * HSZ) + ssl;

      // stage one chunk (K[kc*32..+32) of each kq quarter, both mats)
      auto stage = [&](int kc, int bsel) {
        char* d = smem + bsel * BUFB + dstb;
        const int kb = kc * 64;
#pragma unroll
        for (int it = 0; it < 4; ++it) {
          const char* src = (it >> 1 ? p1 : p0) +
                            (((2 * it + hi) & 3) << 9) + kb;
          gload16(src, d + it * 8192);
        }
      };

      f32x4 acc[4][4] = {};   // [mt][g]

      stage(0, 0);
      __syncthreads();

      const int rdoff = (mat * 4 + kq) * 4096;
#pragma unroll
      for (int kc = 0; kc < 8; ++kc) {
        if (kc < 7) stage(kc + 1, (kc + 1) & 1);
        const char* sec = smem + (kc & 1) * BUFB + rdoff;
        half8 a[4];
#pragma unroll
        for (int mt = 0; mt < 4; ++mt)
          a[mt] = *(const half8*)(sec + (mt * 16 + ln15) * 64 + lq * 16);
#pragma unroll
        for (int g = 0; g < 4; ++g)
#pragma unroll
          for (int mt = 0; mt < 4; ++mt)
            acc[mt][g] = __builtin_amdgcn_mfma_f32_16x16x32_f16(
                a[mt], bw[g][kc], acc[mt][g], 0, 0, 0);
        __syncthreads();
      }

      // ---- kq-plane reduction (mat0 writes, mat1 accumulates) ----
      // C/D map (r3-verified): C row = batch = mt*16+lq*4+r,
      // C col = gate-row v = g*16+ln15. bp = b ^ ((ln15&7)<<2) (r7-proven).
      if (mat == 0) {
#pragma unroll
        for (int mt = 0; mt < 4; ++mt)
#pragma unroll
          for (int g = 0; g < 4; ++g) {
            const int v  = g * 16 + ln15;
            const int bp = (mt * 16 + lq * 4) ^ ((ln15 & 7) << 2);
            *(f32x4*)&pl[kq * 4096 + v * 64 + bp] = acc[mt][g];
          }
      }
      __syncthreads();
      if (mat == 1) {
#pragma unroll
        for (int mt = 0; mt < 4; ++mt)
#pragma unroll
          for (int g = 0; g < 4; ++g) {
            const int v  = g * 16 + ln15;
            const int bp = (mt * 16 + lq * 4) ^ ((ln15 & 7) << 2);
            f32x4* p = (f32x4*)&pl[kq * 4096 + v * 64 + bp];
            *p = *p + acc[mt][g];
          }
      }
      __syncthreads();

      // ---- gate math (fp32): thread owns (gb, cols gc/gc+1) ----
      {
        float z[4][2];
#pragma unroll
        for (int g = 0; g < 4; ++g)
#pragma unroll
          for (int j = 0; j < 2; ++j) {
            const int v  = g * 16 + gc + j;
            const int bp = gb ^ ((v & 7) << 2);
            z[g][j] = pl[0 * 4096 + v * 64 + bp] +
                      pl[1 * 4096 + v * 64 + bp] +
                      pl[2 * 4096 + v * 64 + bp] +
                      pl[3 * 4096 + v * 64 + bp] + bsg[g][j];
          }
        float cn0 = fsig(z[1][0]) * cr0 + fsig(z[0][0]) * ftanh(z[2][0]);
        float cn1 = fsig(z[1][1]) * cr1 + fsig(z[0][1]) * ftanh(z[2][1]);
        float hn0 = fsig(z[3][0]) * ftanh(cn0);
        float hn1 = fsig(z[3][1]) * ftanh(cn1);
        cr0 = cn0; cr1 = cn1;
        half2v hv; hv[0] = (_Float16)hn0; hv[1] = (_Float16)hn1;
        const size_t ho = (size_t)(s & 1) * (LSZ * BSZ * HSZ) +
                          (size_t)l * (BSZ * HSZ) + (size_t)gb * HSZ + c0 + gc;
        __hip_atomic_store((unsigned*)(h16 + ho),
                           __builtin_bit_cast(unsigned, hv),
                           __ATOMIC_RELAXED, __HIP_MEMORY_SCOPE_AGENT);
        if (l == LSZ - 1 && t == TSZ - 1) {
          out[(size_t)gb * HSZ + c0 + gc]     = hn0;
          out[(size_t)gb * HSZ + c0 + gc + 1] = hn1;
        }
      }
    }
    gbar(flags, btgt++);
  }
}

extern "C" void kernel_launch(void* const* d_in, const int* in_sizes, int n_in,
                              void* d_out, int out_size, void* d_ws, size_t ws_size,
                              hipStream_t stream) {
  const float* x   = (const float*)d_in[0];
  const float* Wih = (const float*)d_in[1];
  const float* Whh = (const float*)d_in[2];
  const float* bih = (const float*)d_in[3];
  const float* bhh = (const float*)d_in[4];
  float* out = (float*)d_out;
  char*  ws  = (char*)d_ws;

  // barrier flags zeroed every call (captured in graph -> re-zeroed per replay)
  hipMemsetAsync(ws + OFF_FLAGS, 0, BAR_BYTES, stream);

  void* args[] = {(void*)&x, (void*)&Wih, (void*)&Whh, (void*)&bih,
                  (void*)&bhh, (void*)&out, (void*)&ws};
  hipLaunchCooperativeKernel((const void*)lstm_persistent, dim3(NBLK), dim3(NTHR),
                             args, 0, stream);
}

// Round 14
// 5856.843 us; speedup vs baseline: 1.0355x; 1.0355x over previous
//
#include <hip/hip_runtime.h>
#include <math.h>

// ---------------------------------------------------------------------------
// 4-layer LSTM, B=64 T=512 D=H=1024. Persistent cooperative kernel, wavefront
// schedule (layer l works on t = s - l). Round-14 = r13's wave role with
// r12's PROVEN bank geometry (r13's 64B rows concentrated each half-wave on
// 16 banks -> 4.7x conflicts; the fix is r12's XOR form on 256B rows).
//   - Wave role {mat(2) x kq(4)}, all 4 gates/wave: bw[4][8]=128, acc[4][4]
//     =64. Each A-fragment feeds 4 MFMAs; A-read traffic 256 KB/step/CU.
//     K ownership interleaved: wave kq owns k = kc*128 + [kq*32, kq*32+32)
//     per chunk kc -> ALL waves compute EVERY chunk (pipeline preserved).
//   - Chunk layout [mat][b(64)][256B] (rows = 0 mod 32 banks). Read offset
//     (kq*64 + lq*16) ^ ((row&7)<<4): quad = ((kq&1)*4+lq)^(row&7) spreads
//     each half-wave uniformly (4 dwords/bank) -- the r12-measured pattern.
//   - Staging: 4 gload16/thread; dest LINEAR (it*8192 + w*1024 + lane*16);
//     source slot pre-swizzled (sl&8)|((sl&7)^(b&7)), b&7 thread-constant.
//     Read-XOR o write-preswizzle verified = identity.
// Unchanged from r12/r13 (verified): coalesced gate mapping gb=tid>>3
// (h-store 8x32B bursts -- the r12 2.18GB->0.35GB fix), 4 kq-plane reduction
// with bp=b^((ln15&7)<<2), fast gates, relaxed-agent single-hop barrier +
// one acquire fence, h16 parity double-buffer, c-state in registers.
// ---------------------------------------------------------------------------

#define BSZ 64
#define TSZ 512
#define DSZ 1024
#define HSZ 1024
#define LSZ 4
#define NBLK 256
#define NTHR 512
#define NSTEP (TSZ + LSZ - 1)   // 515
#define BUFB 32768               // bytes per LDS staging buffer

typedef _Float16 half8  __attribute__((ext_vector_type(8)));
typedef _Float16 half4  __attribute__((ext_vector_type(4)));
typedef _Float16 half2v __attribute__((ext_vector_type(2)));
typedef float    f32x4  __attribute__((ext_vector_type(4)));
typedef float    f32x8  __attribute__((ext_vector_type(8)));

// workspace layout (bytes)
constexpr size_t N_X  = (size_t)BSZ * TSZ * DSZ;       // halfs
constexpr size_t N_H  = (size_t)2 * LSZ * BSZ * HSZ;   // halfs (h double buffer)
constexpr size_t OFF_X     = 0;
constexpr size_t OFF_H     = OFF_X + N_X * 2;
constexpr size_t OFF_FLAGS = OFF_H + N_H * 2;          // 256 flags, 64B apart
constexpr size_t BAR_BYTES = (size_t)NBLK * 64;

// fast gates (r11/r12-verified: absmax unchanged at 4.88e-4)
__device__ inline float fsig(float x) {
  return __builtin_amdgcn_rcpf(1.0f + __expf(-x));
}
__device__ inline float ftanh(float x) {
  float e = __expf(fminf(2.0f * x, 80.0f));
  return 1.0f - 2.0f * __builtin_amdgcn_rcpf(e + 1.0f);
}

__device__ inline void gload16(const void* g, void* l) {
  __builtin_amdgcn_global_load_lds(
      (const __attribute__((address_space(1))) void*)g,
      (__attribute__((address_space(3))) void*)l, 16, 0, 0);
}

// Single-hop all-poll grid barrier (r6-r13-verified).
__device__ inline void gbar(unsigned* flags, unsigned tgt) {
  __syncthreads();
  const int t = threadIdx.x;
  if (t == 0)
    __hip_atomic_store(&flags[(size_t)blockIdx.x * 16], tgt, __ATOMIC_RELAXED,
                       __HIP_MEMORY_SCOPE_AGENT);
  if (t < NBLK) {
    while (__hip_atomic_load(&flags[(size_t)t * 16], __ATOMIC_RELAXED,
                             __HIP_MEMORY_SCOPE_AGENT) < tgt)
      __builtin_amdgcn_s_sleep(2);
  }
  __syncthreads();
  if (t == 0) __builtin_amdgcn_fence(__ATOMIC_ACQUIRE, "agent");
  __syncthreads();
}

__global__ __launch_bounds__(NTHR, 1) void lstm_persistent(
    const float* __restrict__ xin, const float* __restrict__ Wih,
    const float* __restrict__ Whh, const float* __restrict__ bih,
    const float* __restrict__ bhh, float* __restrict__ out,
    char* __restrict__ ws)
{
  _Float16* x16   = (_Float16*)(ws + OFF_X);
  _Float16* h16   = (_Float16*)(ws + OFF_H);
  unsigned* flags = (unsigned*)(ws + OFF_FLAGS);

  const int tid  = threadIdx.x;
  const int gtid = blockIdx.x * NTHR + tid;
  const int lane = tid & 63;
  const int w    = tid >> 6;        // wave 0..7
  const int mat  = w >> 2;          // 0 = input-side, 1 = recurrent
  const int kq   = w & 3;           // K-quarter (interleaved slices)
  const int ln15 = lane & 15;
  const int lq   = lane >> 4;

  const int l  = blockIdx.x >> 6;   // layer
  const int cc = blockIdx.x & 63;   // column chunk (16 H-cols)
  const int c0 = cc * 16;

  // ---- weight preload (fp32 -> fp16, one time) ----
  // B-frag (r3-r13-verified convention): lane holds W[row = gate g,
  // col c0+ln15] at k = kc*128 + kq*32 + lq*8 + 0..7 (interleaved slices).
  const float* Wsel = mat ? Whh : Wih;
  half8 bw[4][8];
#pragma unroll
  for (int g = 0; g < 4; ++g) {
    const float* wrow =
        Wsel + (size_t)(l * 4096 + g * 1024 + c0 + ln15) * 1024 +
        kq * 32 + lq * 8;
#pragma unroll
    for (int kc = 0; kc < 8; ++kc) {
      f32x8 f = *(const f32x8*)(wrow + kc * 128);
      bw[g][kc] = __builtin_convertvector(f, half8);
    }
  }

  // ---- gate-math ownership (coalesced, r12-verified): row gb, cols gc/gc+1
  const int gb = tid >> 3;          // batch row 0..63
  const int gc = (tid & 7) * 2;     // even col 0..14
  float bsg[4][2];
#pragma unroll
  for (int g = 0; g < 4; ++g) {
    const int bb = l * 4096 + g * 1024 + c0 + gc;
    bsg[g][0] = bih[bb] + bhh[bb];
    bsg[g][1] = bih[bb + 1] + bhh[bb + 1];
  }
  float cr0 = 0.f, cr1 = 0.f;       // block-private c-state (registers)

  // ---- staging decomposition (step-invariant) ----
  // Chunk = [mat(2)][b(64)][16 sl x 16B] = 32KB, LDS LINEAR:
  // dest(it) = bsel*BUFB + it*8192 + w*1024 + lane*16
  //          = mat(it)*16384 + b(it)*256 + ln15*16,
  // with mat(it)=it>>1, b(it)=(it&1)*32 + w*4 + lq, sl=ln15.
  // Source slot pre-swizzled: (sl&8)|((sl&7)^(b&7)); b&7 = 4*(w&1)+lq
  // (it-independent). Read applies the same XOR -> identity.
  const int b_e   = w * 4 + lq;                 // b for even it
  const int b7    = 4 * (w & 1) + lq;           // = b&7 (both its)
  const int ssl   = ((ln15 & 8) | ((ln15 & 7) ^ b7)) << 4;  // src byte in row
  const int dstb  = w * 1024 + lane * 16;       // linear LDS dest base

  // ---- pre-phase: cast x to fp16, zero h — relaxed agent stores ----
  {
    const f32x4* s4 = (const f32x4*)xin;
    unsigned long long* xu = (unsigned long long*)x16;
    for (int i = gtid; i < (int)(N_X / 4); i += NBLK * NTHR) {
      half4 v = __builtin_convertvector(s4[i], half4);
      __hip_atomic_store(&xu[i], __builtin_bit_cast(unsigned long long, v),
                         __ATOMIC_RELAXED, __HIP_MEMORY_SCOPE_AGENT);
    }
    unsigned long long* hz = (unsigned long long*)h16;
    for (int i = gtid; i < (int)(N_H / 4); i += NBLK * NTHR)
      __hip_atomic_store(&hz[i], 0ull, __ATOMIC_RELAXED,
                         __HIP_MEMORY_SCOPE_AGENT);
  }
  unsigned btgt = 1;
  gbar(flags, btgt++);

  // ---- LDS: 2 staging buffers (32KB); 4 kq-planes overlay both (64KB) ----
  __shared__ __align__(16) char smem[2 * BUFB];
  float* pl = (float*)smem;        // f32[4][64][64] after final compute sync

  const int lm1 = (l > 0) ? (l - 1) : 0;

  for (int s = 0; s < NSTEP; ++s) {
    const int t = s - l;
    if (t >= 0 && t < TSZ) {
      const int prevslot = (s + 1) & 1;
      const _Float16* hin  = h16 + (size_t)prevslot * (LSZ * BSZ * HSZ) +
                             (size_t)lm1 * (BSZ * HSZ);
      const _Float16* hown = h16 + (size_t)prevslot * (LSZ * BSZ * HSZ) +
                             (size_t)l * (BSZ * HSZ);
      const _Float16* base0 = (l == 0) ? x16 + (size_t)t * DSZ : hin;
      const size_t    str0  = (l == 0) ? (size_t)TSZ * DSZ : (size_t)HSZ;

      // my 4 source rows (mat0/mat1 x b_e/b_e+32), pre-swizzled slot
      const char* p00 = (const char*)(base0 + (size_t)b_e * str0) + ssl;
      const char* p01 = (const char*)(base0 + (size_t)(b_e + 32) * str0) + ssl;
      const char* p10 = (const char*)(hown + (size_t)b_e * HSZ) + ssl;
      const char* p11 = (const char*)(hown + (size_t)(b_e + 32) * HSZ) + ssl;

      // stage one chunk (K[kc*128..+128) of both mats)
      auto stage = [&](int kc, int bsel) {
        char* d = smem + bsel * BUFB + dstb;
        const int kb = kc * 256;
        gload16(p00 + kb, d);
        gload16(p01 + kb, d + 8192);
        gload16(p10 + kb, d + 16384);
        gload16(p11 + kb, d + 24576);
      };

      f32x4 acc[4][4] = {};   // [mt][g]

      stage(0, 0);
      __syncthreads();

      const int rdsec = mat * 16384;
      const int rdo   = kq * 64 + lq * 16;   // pre-XOR byte offset in row
#pragma unroll
      for (int kc = 0; kc < 8; ++kc) {
        if (kc < 7) stage(kc + 1, (kc + 1) & 1);
        const char* sec = smem + (kc & 1) * BUFB + rdsec;
        half8 a[4];
#pragma unroll
        for (int mt = 0; mt < 4; ++mt) {
          const int row = mt * 16 + ln15;
          a[mt] = *(const half8*)(sec + row * 256 +
                                  (rdo ^ ((row & 7) << 4)));
        }
#pragma unroll
        for (int g = 0; g < 4; ++g)
#pragma unroll
          for (int mt = 0; mt < 4; ++mt)
            acc[mt][g] = __builtin_amdgcn_mfma_f32_16x16x32_f16(
                a[mt], bw[g][kc], acc[mt][g], 0, 0, 0);
        __syncthreads();
      }

      // ---- kq-plane reduction (mat0 writes, mat1 accumulates) ----
      // C/D map (r3-verified): C row = batch = mt*16+lq*4+r,
      // C col = gate-row v = g*16+ln15. bp = b ^ ((ln15&7)<<2) (r7-proven).
      if (mat == 0) {
#pragma unroll
        for (int mt = 0; mt < 4; ++mt)
#pragma unroll
          for (int g = 0; g < 4; ++g) {
            const int v  = g * 16 + ln15;
            const int bp = (mt * 16 + lq * 4) ^ ((ln15 & 7) << 2);
            *(f32x4*)&pl[kq * 4096 + v * 64 + bp] = acc[mt][g];
          }
      }
      __syncthreads();
      if (mat == 1) {
#pragma unroll
        for (int mt = 0; mt < 4; ++mt)
#pragma unroll
          for (int g = 0; g < 4; ++g) {
            const int v  = g * 16 + ln15;
            const int bp = (mt * 16 + lq * 4) ^ ((ln15 & 7) << 2);
            f32x4* p = (f32x4*)&pl[kq * 4096 + v * 64 + bp];
            *p = *p + acc[mt][g];
          }
      }
      __syncthreads();

      // ---- gate math (fp32): thread owns (gb, cols gc/gc+1) ----
      {
        float z[4][2];
#pragma unroll
        for (int g = 0; g < 4; ++g)
#pragma unroll
          for (int j = 0; j < 2; ++j) {
            const int v  = g * 16 + gc + j;
            const int bp = gb ^ ((v & 7) << 2);
            z[g][j] = pl[0 * 4096 + v * 64 + bp] +
                      pl[1 * 4096 + v * 64 + bp] +
                      pl[2 * 4096 + v * 64 + bp] +
                      pl[3 * 4096 + v * 64 + bp] + bsg[g][j];
          }
        float cn0 = fsig(z[1][0]) * cr0 + fsig(z[0][0]) * ftanh(z[2][0]);
        float cn1 = fsig(z[1][1]) * cr1 + fsig(z[0][1]) * ftanh(z[2][1]);
        float hn0 = fsig(z[3][0]) * ftanh(cn0);
        float hn1 = fsig(z[3][1]) * ftanh(cn1);
        cr0 = cn0; cr1 = cn1;
        half2v hv; hv[0] = (_Float16)hn0; hv[1] = (_Float16)hn1;
        const size_t ho = (size_t)(s & 1) * (LSZ * BSZ * HSZ) +
                          (size_t)l * (BSZ * HSZ) + (size_t)gb * HSZ + c0 + gc;
        __hip_atomic_store((unsigned*)(h16 + ho),
                           __builtin_bit_cast(unsigned, hv),
                           __ATOMIC_RELAXED, __HIP_MEMORY_SCOPE_AGENT);
        if (l == LSZ - 1 && t == TSZ - 1) {
          out[(size_t)gb * HSZ + c0 + gc]     = hn0;
          out[(size_t)gb * HSZ + c0 + gc + 1] = hn1;
        }
      }
    }
    gbar(flags, btgt++);
  }
}

extern "C" void kernel_launch(void* const* d_in, const int* in_sizes, int n_in,
                              void* d_out, int out_size, void* d_ws, size_t ws_size,
                              hipStream_t stream) {
  const float* x   = (const float*)d_in[0];
  const float* Wih = (const float*)d_in[1];
  const float* Whh = (const float*)d_in[2];
  const float* bih = (const float*)d_in[3];
  const float* bhh = (const float*)d_in[4];
  float* out = (float*)d_out;
  char*  ws  = (char*)d_ws;

  // barrier flags zeroed every call (captured in graph -> re-zeroed per replay)
  hipMemsetAsync(ws + OFF_FLAGS, 0, BAR_BYTES, stream);

  void* args[] = {(void*)&x, (void*)&Wih, (void*)&Whh, (void*)&bih,
                  (void*)&bhh, (void*)&out, (void*)&ws};
  hipLaunchCooperativeKernel((const void*)lstm_persistent, dim3(NBLK), dim3(NTHR),
                             args, 0, stream);
}

// Round 15
// 4773.445 us; speedup vs baseline: 1.2705x; 1.2270x over previous
//
#include <hip/hip_runtime.h>
#include <math.h>

// ---------------------------------------------------------------------------
// 4-layer LSTM, B=64 T=512 D=H=1024. Persistent cooperative kernel, wavefront
// schedule (layer l works on t = s - l). Round-15 = EXACT round-12 (best
// verified: 4.81ms, conflicts 5e7, no spill) + layer-0 x-locality fix:
//   DIAGNOSIS: r13/r14 dead end (identical conflict counts killed the A-read
//   theory). r12's kc-loop syncthreads force vmcnt(0) drains; layers 1-3
//   stage from L2-resident h (~200cy, hidden), but layer 0 stages a fresh
//   128KB x-slice every step (64MB total, never L2-resident) -> ~500cy
//   stall x 8 chunks. Pipeline throughput = slowest layer => layer 0 gates.
//   FIX (two parts, one mechanism):
//   1. Time-major x16: cast to x16t[t][b][d]; slice t = contiguous 128KB;
//      staging stride uniform (1024) for all layers.
//   2. Prefetch-touch: after the kc loop, l=0 blocks gload16 the NEXT
//      slice's portion ((cc>>3)*16KB; 8 co-XCD blocks cover 128KB) into a
//      dead buf1 trash region -> next step's staging hits L2.
// Unchanged from r12 (verified): wave role {mat x gatepair x Khalf},
// bw[2][16]=128 regs, acc[4][2]; gload_lds staging (linear dest, inverse-
// swizzled source); kh-plane reduction bp=b^((v&7)<<2); coalesced gate
// mapping gb=tid>>3 (h-store 8x32B bursts); fast gates; relaxed-agent
// single-hop barrier + one acquire fence; h16 parity double-buffer;
// c-state in registers.
// ---------------------------------------------------------------------------

#define BSZ 64
#define TSZ 512
#define DSZ 1024
#define HSZ 1024
#define LSZ 4
#define NBLK 256
#define NTHR 512
#define NSTEP (TSZ + LSZ - 1)   // 515
#define BUFB 32768               // bytes per LDS staging buffer

typedef _Float16 half8  __attribute__((ext_vector_type(8)));
typedef _Float16 half4  __attribute__((ext_vector_type(4)));
typedef _Float16 half2v __attribute__((ext_vector_type(2)));
typedef float    f32x4  __attribute__((ext_vector_type(4)));
typedef float    f32x8  __attribute__((ext_vector_type(8)));

// workspace layout (bytes)
constexpr size_t N_X  = (size_t)BSZ * TSZ * DSZ;       // halfs
constexpr size_t N_H  = (size_t)2 * LSZ * BSZ * HSZ;   // halfs (h double buffer)
constexpr size_t OFF_X     = 0;
constexpr size_t OFF_H     = OFF_X + N_X * 2;
constexpr size_t OFF_FLAGS = OFF_H + N_H * 2;          // 256 flags, 64B apart
constexpr size_t BAR_BYTES = (size_t)NBLK * 64;

// fast gates (r11/r12-verified: absmax unchanged at 4.88e-4)
__device__ inline float fsig(float x) {
  return __builtin_amdgcn_rcpf(1.0f + __expf(-x));
}
__device__ inline float ftanh(float x) {
  float e = __expf(fminf(2.0f * x, 80.0f));
  return 1.0f - 2.0f * __builtin_amdgcn_rcpf(e + 1.0f);
}

__device__ inline void gload16(const void* g, void* l) {
  __builtin_amdgcn_global_load_lds(
      (const __attribute__((address_space(1))) void*)g,
      (__attribute__((address_space(3))) void*)l, 16, 0, 0);
}

// Single-hop all-poll grid barrier (r6-r14-verified).
__device__ inline void gbar(unsigned* flags, unsigned tgt) {
  __syncthreads();
  const int t = threadIdx.x;
  if (t == 0)
    __hip_atomic_store(&flags[(size_t)blockIdx.x * 16], tgt, __ATOMIC_RELAXED,
                       __HIP_MEMORY_SCOPE_AGENT);
  if (t < NBLK) {
    while (__hip_atomic_load(&flags[(size_t)t * 16], __ATOMIC_RELAXED,
                             __HIP_MEMORY_SCOPE_AGENT) < tgt)
      __builtin_amdgcn_s_sleep(2);
  }
  __syncthreads();
  if (t == 0) __builtin_amdgcn_fence(__ATOMIC_ACQUIRE, "agent");
  __syncthreads();
}

__global__ __launch_bounds__(NTHR, 1) void lstm_persistent(
    const float* __restrict__ xin, const float* __restrict__ Wih,
    const float* __restrict__ Whh, const float* __restrict__ bih,
    const float* __restrict__ bhh, float* __restrict__ out,
    char* __restrict__ ws)
{
  _Float16* x16   = (_Float16*)(ws + OFF_X);   // TIME-MAJOR: [t][b][d]
  _Float16* h16   = (_Float16*)(ws + OFF_H);
  unsigned* flags = (unsigned*)(ws + OFF_FLAGS);

  const int tid  = threadIdx.x;
  const int gtid = blockIdx.x * NTHR + tid;
  const int lane = tid & 63;
  const int w    = tid >> 6;        // wave 0..7
  const int mat  = w >> 2;          // 0 = input-side, 1 = recurrent
  const int rp   = (w >> 1) & 1;    // gate pair (gates 2rp, 2rp+1)
  const int kh   = w & 1;           // K-half (512 k's)
  const int ln15 = lane & 15;
  const int lq   = lane >> 4;

  const int l  = blockIdx.x >> 6;   // layer
  const int cc = blockIdx.x & 63;   // column chunk (16 H-cols)
  const int c0 = cc * 16;

  // ---- weight preload into registers (fp32 -> fp16, one time) ----
  // B-frag (r3-r12-verified): lane holds W[row = gate 2rp+gl, col c0+ln15]
  // at k = kh*512 + ks*32 + lq*8 + 0..7. bw[gl][ks] = 128 regs.
  const float* Wsel = mat ? Whh : Wih;
  half8 bw[2][16];
#pragma unroll
  for (int gl = 0; gl < 2; ++gl) {
    const float* wrow =
        Wsel + (size_t)(l * 4096 + (rp * 2 + gl) * 1024 + c0 + ln15) * 1024 +
        kh * 512;
#pragma unroll
    for (int ks = 0; ks < 16; ++ks) {
      f32x8 f = *(const f32x8*)(wrow + ks * 32 + lq * 8);
      bw[gl][ks] = __builtin_convertvector(f, half8);
    }
  }

  // ---- gate-math ownership (coalesced, r12-verified): row gb, cols gc/gc+1
  const int gb = tid >> 3;          // batch row 0..63
  const int gc = (tid & 7) * 2;     // even col 0..14
  float bsg[4][2];
#pragma unroll
  for (int g = 0; g < 4; ++g) {
    const int bb = l * 4096 + g * 1024 + c0 + gc;
    bsg[g][0] = bih[bb] + bhh[bb];
    bsg[g][1] = bih[bb + 1] + bhh[bb + 1];
  }
  float cr0 = 0.f, cr1 = 0.f;       // block-private c-state (registers)

  // ---- staging decomposition (step-invariant, r12-verified) ----
  // Chunk layout: [mat][kh][b(64)][8 slots x 16B] = 32KB, LDS LINEAR.
  // Per gload16 call: (mat,kh) wave-uniform; lane covers b=tid>>3, sl=tid&7.
  // Source slot pre-swizzled: sl_g = sl ^ (b&7)  (read applies same XOR).
  const int sb   = tid >> 3;                        // my staging batch row
  const int pswl = ((tid & 7) ^ (sb & 7)) << 4;     // swizzled source slot*16
  const int dstb = (tid >> 6) << 10;                // wave LDS base (w*1024)

  // ---- pre-phase: cast x to TIME-MAJOR fp16, zero h ----
  {
    const f32x4* s4 = (const f32x4*)xin;
    unsigned long long* xu = (unsigned long long*)x16;
    const int dq = DSZ / 4;                         // 256 (pow2)
    for (int i = gtid; i < (int)(N_X / 4); i += NBLK * NTHR) {
      const int d4  = i & (dq - 1);
      const int rem = i >> 8;                       // i / dq
      const int tt  = rem & (TSZ - 1);
      const int bb  = rem >> 9;                     // rem / TSZ
      half4 v = __builtin_convertvector(s4[i], half4);
      const size_t o = ((size_t)tt * BSZ + bb) * dq + d4;
      __hip_atomic_store(&xu[o], __builtin_bit_cast(unsigned long long, v),
                         __ATOMIC_RELAXED, __HIP_MEMORY_SCOPE_AGENT);
    }
    unsigned long long* hz = (unsigned long long*)h16;
    for (int i = gtid; i < (int)(N_H / 4); i += NBLK * NTHR)
      __hip_atomic_store(&hz[i], 0ull, __ATOMIC_RELAXED,
                         __HIP_MEMORY_SCOPE_AGENT);
  }
  unsigned btgt = 1;
  gbar(flags, btgt++);

  // ---- LDS: 2 staging buffers (32KB each); planes overlay buf0 ----
  __shared__ __align__(16) char smem[2 * BUFB];
  float* pl = (float*)smem;        // f32[2][64][64] after final compute sync

  const int lm1 = (l > 0) ? (l - 1) : 0;

  for (int s = 0; s < NSTEP; ++s) {
    const int t = s - l;
    if (t >= 0 && t < TSZ) {
      const int prevslot = (s + 1) & 1;
      const _Float16* hin  = h16 + (size_t)prevslot * (LSZ * BSZ * HSZ) +
                             (size_t)lm1 * (BSZ * HSZ);
      const _Float16* hown = h16 + (size_t)prevslot * (LSZ * BSZ * HSZ) +
                             (size_t)l * (BSZ * HSZ);
      // time-major: layer-0 slice t is contiguous [64b][1024d]; stride 1024
      // for ALL layers now.
      const _Float16* base0 = (l == 0) ? x16 + (size_t)t * (BSZ * DSZ) : hin;

      // my two source rows for staging (mat0-side, mat1-side), + swizzle
      const char* p0 = (const char*)(base0 + (size_t)sb * 1024) + pswl;
      const char* p1 = (const char*)(hown + (size_t)sb * HSZ) + pswl;

      // stage one chunk (K[kc*64..+64) of both K-halves, both mats) into
      // buf[bsel] via async global->LDS; drained by the next __syncthreads.
      auto stage = [&](int kc, int bsel) {
        const char* r0 = p0 + kc * 128;
        const char* r1 = p1 + kc * 128;
        char* d = smem + bsel * BUFB + dstb;
        gload16(r0,        d);           // (mat0, kh0)
        gload16(r0 + 1024, d + 8192);    // (mat0, kh1)
        gload16(r1,        d + 16384);   // (mat1, kh0)
        gload16(r1 + 1024, d + 24576);   // (mat1, kh1)
      };

      f32x4 acc[4][2] = {};   // [mt][gl]

      stage(0, 0);
      __syncthreads();

      const int rdoff = mat * 16384 + kh * 8192;
#pragma unroll
      for (int kc = 0; kc < 8; ++kc) {
        if (kc < 7) stage(kc + 1, (kc + 1) & 1);
        const char* rdb = smem + (kc & 1) * BUFB + rdoff;
#pragma unroll
        for (int ksl = 0; ksl < 2; ++ksl) {
#pragma unroll
          for (int mt = 0; mt < 4; ++mt) {
            const int row = mt * 16 + ln15;
            const half8 a = *(const half8*)(rdb + row * 128 +
                                            ((ksl * 64 + lq * 16) ^
                                             ((row & 7) << 4)));
            acc[mt][0] = __builtin_amdgcn_mfma_f32_16x16x32_f16(
                a, bw[0][kc * 2 + ksl], acc[mt][0], 0, 0, 0);
            acc[mt][1] = __builtin_amdgcn_mfma_f32_16x16x32_f16(
                a, bw[1][kc * 2 + ksl], acc[mt][1], 0, 0, 0);
          }
        }
        __syncthreads();
      }

      // ---- layer-0 prefetch-touch of NEXT x-slice into L2 ----
      // buf1 is dead after the kc loop (last reads were iter 7, pre-sync).
      // Portion (cc>>3)*16KB: the 8 l=0 blocks per XCD cover the full 128KB.
      // Drains at the next syncthreads (~one L3 latency, l=0 blocks only).
      if (l == 0 && t + 1 < TSZ) {
        const char* xnext =
            (const char*)(x16 + (size_t)(t + 1) * (BSZ * DSZ)) +
            ((cc >> 3) & 7) * 16384;
        char* trash = smem + BUFB + dstb;
        gload16(xnext + tid * 16, trash);
        gload16(xnext + 8192 + tid * 16, trash);
      }

      // ---- kh-plane reduction (mat0 writes, mat1 accumulates) ----
      // C/D map (r3-verified): C row = batch = mt*16+lq*4+r,
      // C col = gate-row v = (2rp+gl)*16+ln15. bp = b ^ ((v&7)<<2).
      if (mat == 0) {
#pragma unroll
        for (int mt = 0; mt < 4; ++mt)
#pragma unroll
          for (int gl = 0; gl < 2; ++gl) {
            const int v  = (rp * 2 + gl) * 16 + ln15;
            const int bp = (mt * 16 + lq * 4) ^ ((ln15 & 7) << 2);
            *(f32x4*)&pl[kh * 4096 + v * 64 + bp] = acc[mt][gl];
          }
      }
      __syncthreads();
      if (mat == 1) {
#pragma unroll
        for (int mt = 0; mt < 4; ++mt)
#pragma unroll
          for (int gl = 0; gl < 2; ++gl) {
            const int v  = (rp * 2 + gl) * 16 + ln15;
            const int bp = (mt * 16 + lq * 4) ^ ((ln15 & 7) << 2);
            f32x4* p = (f32x4*)&pl[kh * 4096 + v * 64 + bp];
            *p = *p + acc[mt][gl];
          }
      }
      __syncthreads();

      // ---- gate math (fp32): thread owns (gb, cols gc/gc+1) ----
      {
        float z[4][2];
#pragma unroll
        for (int g = 0; g < 4; ++g)
#pragma unroll
          for (int j = 0; j < 2; ++j) {
            const int v  = g * 16 + gc + j;
            const int bp = gb ^ ((v & 7) << 2);
            z[g][j] = pl[0 * 4096 + v * 64 + bp] +
                      pl[1 * 4096 + v * 64 + bp] + bsg[g][j];
          }
        float cn0 = fsig(z[1][0]) * cr0 + fsig(z[0][0]) * ftanh(z[2][0]);
        float cn1 = fsig(z[1][1]) * cr1 + fsig(z[0][1]) * ftanh(z[2][1]);
        float hn0 = fsig(z[3][0]) * ftanh(cn0);
        float hn1 = fsig(z[3][1]) * ftanh(cn1);
        cr0 = cn0; cr1 = cn1;
        half2v hv; hv[0] = (_Float16)hn0; hv[1] = (_Float16)hn1;
        const size_t ho = (size_t)(s & 1) * (LSZ * BSZ * HSZ) +
                          (size_t)l * (BSZ * HSZ) + (size_t)gb * HSZ + c0 + gc;
        __hip_atomic_store((unsigned*)(h16 + ho),
                           __builtin_bit_cast(unsigned, hv),
                           __ATOMIC_RELAXED, __HIP_MEMORY_SCOPE_AGENT);
        if (l == LSZ - 1 && t == TSZ - 1) {
          out[(size_t)gb * HSZ + c0 + gc]     = hn0;
          out[(size_t)gb * HSZ + c0 + gc + 1] = hn1;
        }
      }
    }
    gbar(flags, btgt++);
  }
}

extern "C" void kernel_launch(void* const* d_in, const int* in_sizes, int n_in,
                              void* d_out, int out_size, void* d_ws, size_t ws_size,
                              hipStream_t stream) {
  const float* x   = (const float*)d_in[0];
  const float* Wih = (const float*)d_in[1];
  const float* Whh = (const float*)d_in[2];
  const float* bih = (const float*)d_in[3];
  const float* bhh = (const float*)d_in[4];
  float* out = (float*)d_out;
  char*  ws  = (char*)d_ws;

  // barrier flags zeroed every call (captured in graph -> re-zeroed per replay)
  hipMemsetAsync(ws + OFF_FLAGS, 0, BAR_BYTES, stream);

  void* args[] = {(void*)&x, (void*)&Wih, (void*)&Whh, (void*)&bih,
                  (void*)&bhh, (void*)&out, (void*)&ws};
  hipLaunchCooperativeKernel((const void*)lstm_persistent, dim3(NBLK), dim3(NTHR),
                             args, 0, stream);
}